// Round 1
// baseline (915.363 us; speedup 1.0000x reference)
//
#include <hip/hip_runtime.h>
#include <math.h>

// CoreAttention  B=2 S=2048 H=16 D=64
// Flash-style fused attention, f16 MFMA with hi/lo split on QK^T for accuracy.
// Memory-bound on the 512MB attn_bias stream -> target ~100-150us.

namespace {
constexpr int Bn = 2, Sn = 2048, Hn = 16, Dn = 64;
constexpr int QT = 64;   // q rows per block (4 waves x 16)
constexpr int KT = 64;   // keys per tile
constexpr int ST = 72;   // LDS row stride in f16 (pad 64->72: uniform bank windows, keeps 16B align)

typedef _Float16 f16x8 __attribute__((ext_vector_type(8)));
typedef float    f32x4 __attribute__((ext_vector_type(4)));
}

__global__ __launch_bounds__(256, 4)
void core_attn_kernel(const float* __restrict__ Q,
                      const float* __restrict__ K,
                      const float* __restrict__ V,
                      const float* __restrict__ Bias,
                      const int*   __restrict__ Mask,
                      float* __restrict__ Out)
{
    const int qt = blockIdx.x;   // 0..31
    const int h  = blockIdx.y;   // 0..15
    const int b  = blockIdx.z;   // 0..1
    const int q0 = qt * QT;

    const int tid  = threadIdx.x;
    const int wave = tid >> 6;   // 0..3
    const int lane = tid & 63;
    const int c    = lane & 15;  // n/m index within 16-tile
    const int quad = lane >> 4;  // 0..3

    __shared__ __align__(16) _Float16 Khi[KT * ST];
    __shared__ __align__(16) _Float16 Klo[KT * ST];
    __shared__ __align__(16) _Float16 Vt [Dn * ST];   // V transposed: Vt[d][kc]
    __shared__ __align__(16) _Float16 Pl [4][16 * ST];

    // ---- Q fragments (A layout: m=lane&15, k=quad*8+j), scaled by sqrt(D)=8, hi/lo split
    f16x8 qhi[2], qlo[2];
    {
        const int qrow = q0 + wave * 16 + c;
        const float* qp = Q + ((size_t)((b * Sn + qrow) * Hn + h)) * Dn + quad * 8;
        #pragma unroll
        for (int kc = 0; kc < 2; ++kc) {
            float4 v0 = *(const float4*)(qp + kc * 32);
            float4 v1 = *(const float4*)(qp + kc * 32 + 4);
            float buf[8] = {v0.x, v0.y, v0.z, v0.w, v1.x, v1.y, v1.z, v1.w};
            #pragma unroll
            for (int j = 0; j < 8; ++j) {
                float f = buf[j] * 8.0f;
                _Float16 hi = (_Float16)f;
                qhi[kc][j] = hi;
                qlo[kc][j] = (_Float16)(f - (float)hi);
            }
        }
    }

    f32x4 Oa[4];
    float m_i[4], l_i[4];
    #pragma unroll
    for (int r = 0; r < 4; ++r) { m_i[r] = -INFINITY; l_i[r] = 0.0f; }
    #pragma unroll
    for (int t = 0; t < 4; ++t) Oa[t] = (f32x4){0.f, 0.f, 0.f, 0.f};

    // bias/mask row bases for this lane's C-layout rows (row = quad*4 + r)
    const float* bias_row = Bias + ((size_t)(b * Hn + h) * Sn + (q0 + wave * 16 + quad * 4)) * Sn;
    const int*   mask_row = Mask + ((size_t)(b * Sn + (q0 + wave * 16 + quad * 4))) * Sn;

    // staging: thread -> (row srow, 16-wide d segment)
    const int srow = tid >> 2;            // 0..63
    const int dseg = (tid & 3) * 16;
    const float* kbase = K + ((size_t)((b * Sn + srow) * Hn + h)) * Dn + dseg;
    const float* vbase = V + ((size_t)((b * Sn + srow) * Hn + h)) * Dn + dseg;

    for (int k0 = 0; k0 < Sn; k0 += KT) {
        __syncthreads();
        // ---- stage K (hi/lo) and V^T into LDS as f16
        {
            const float* kp = kbase + (size_t)k0 * (Hn * Dn);
            const float* vp = vbase + (size_t)k0 * (Hn * Dn);
            float4 kv[4], vv[4];
            #pragma unroll
            for (int i = 0; i < 4; ++i) kv[i] = *(const float4*)(kp + 4 * i);
            #pragma unroll
            for (int i = 0; i < 4; ++i) vv[i] = *(const float4*)(vp + 4 * i);
            f16x8 khiv[2], klov[2];
            const float* kf = (const float*)kv;
            #pragma unroll
            for (int j = 0; j < 16; ++j) {
                float f = kf[j];
                _Float16 hi = (_Float16)f;
                khiv[j >> 3][j & 7] = hi;
                klov[j >> 3][j & 7] = (_Float16)(f - (float)hi);
            }
            *(f16x8*)&Khi[srow * ST + dseg]     = khiv[0];
            *(f16x8*)&Khi[srow * ST + dseg + 8] = khiv[1];
            *(f16x8*)&Klo[srow * ST + dseg]     = klov[0];
            *(f16x8*)&Klo[srow * ST + dseg + 8] = klov[1];
            const float* vf = (const float*)vv;
            #pragma unroll
            for (int j = 0; j < 16; ++j)
                Vt[(dseg + j) * ST + srow] = (_Float16)vf[j];
        }
        __syncthreads();

        // ---- scores: this wave's 16 rows x 64 cols; bias preloaded as MFMA C operand
        float sc[4][4];   // [col-tile][reg]; C layout: row=quad*4+reg, col=ct*16+c
        #pragma unroll
        for (int ct = 0; ct < 4; ++ct) {
            f32x4 acc;
            #pragma unroll
            for (int r = 0; r < 4; ++r)
                acc[r] = bias_row[(size_t)r * Sn + k0 + ct * 16 + c];
            #pragma unroll
            for (int kc = 0; kc < 2; ++kc) {
                f16x8 kh = *(const f16x8*)&Khi[(ct * 16 + c) * ST + kc * 32 + quad * 8];
                f16x8 kl = *(const f16x8*)&Klo[(ct * 16 + c) * ST + kc * 32 + quad * 8];
                acc = __builtin_amdgcn_mfma_f32_16x16x32_f16(qhi[kc], kh, acc, 0, 0, 0);
                acc = __builtin_amdgcn_mfma_f32_16x16x32_f16(qhi[kc], kl, acc, 0, 0, 0);
                acc = __builtin_amdgcn_mfma_f32_16x16x32_f16(qlo[kc], kh, acc, 0, 0, 0);
            }
            #pragma unroll
            for (int r = 0; r < 4; ++r) {
                int mv = mask_row[(size_t)r * Sn + k0 + ct * 16 + c];
                sc[ct][r] = mv ? 0.0f : acc[r];
            }
        }

        // ---- online softmax over this tile (rows live in 16 lanes of each quad)
        float mt[4];
        #pragma unroll
        for (int r = 0; r < 4; ++r)
            mt[r] = fmaxf(fmaxf(sc[0][r], sc[1][r]), fmaxf(sc[2][r], sc[3][r]));
        #pragma unroll
        for (int off = 8; off >= 1; off >>= 1) {
            #pragma unroll
            for (int r = 0; r < 4; ++r)
                mt[r] = fmaxf(mt[r], __shfl_xor(mt[r], off, 64));
        }
        float alpha[4], rs[4];
        #pragma unroll
        for (int r = 0; r < 4; ++r) {
            float mn = fmaxf(m_i[r], mt[r]);
            alpha[r] = __expf(m_i[r] - mn);
            m_i[r] = mn;
            rs[r] = 0.0f;
        }
        #pragma unroll
        for (int ct = 0; ct < 4; ++ct) {
            #pragma unroll
            for (int r = 0; r < 4; ++r) {
                float p = __expf(sc[ct][r] - m_i[r]);
                sc[ct][r] = p;
                rs[r] += p;
            }
        }
        #pragma unroll
        for (int off = 8; off >= 1; off >>= 1) {
            #pragma unroll
            for (int r = 0; r < 4; ++r)
                rs[r] += __shfl_xor(rs[r], off, 64);
        }
        #pragma unroll
        for (int r = 0; r < 4; ++r)
            l_i[r] = l_i[r] * alpha[r] + rs[r];
        #pragma unroll
        for (int t = 0; t < 4; ++t) {
            #pragma unroll
            for (int r = 0; r < 4; ++r)
                Oa[t][r] *= alpha[r];
        }

        // ---- P: C layout -> LDS -> A layout (per-wave region, no barrier needed:
        //      DS ops are in-order within a wave)
        #pragma unroll
        for (int ct = 0; ct < 4; ++ct) {
            #pragma unroll
            for (int r = 0; r < 4; ++r)
                Pl[wave][(quad * 4 + r) * ST + ct * 16 + c] = (_Float16)sc[ct][r];
        }
        f16x8 pf[2];
        #pragma unroll
        for (int kc = 0; kc < 2; ++kc)
            pf[kc] = *(const f16x8*)&Pl[wave][c * ST + kc * 32 + quad * 8];

        // ---- O += P @ V   (B frag from Vt: k=kcol contiguous per lane)
        #pragma unroll
        for (int td = 0; td < 4; ++td) {
            #pragma unroll
            for (int kc = 0; kc < 2; ++kc) {
                f16x8 vfrag = *(const f16x8*)&Vt[(td * 16 + c) * ST + kc * 32 + quad * 8];
                Oa[td] = __builtin_amdgcn_mfma_f32_16x16x32_f16(pf[kc], vfrag, Oa[td], 0, 0, 0);
            }
        }
    }

    // ---- epilogue: divide by l, store fp32
    #pragma unroll
    for (int r = 0; r < 4; ++r) l_i[r] = 1.0f / l_i[r];
    float* op = Out + ((size_t)(b * Sn + q0 + wave * 16 + quad * 4)) * (Hn * Dn) + h * Dn + c;
    #pragma unroll
    for (int td = 0; td < 4; ++td) {
        #pragma unroll
        for (int r = 0; r < 4; ++r)
            op[(size_t)r * (Hn * Dn) + td * 16] = Oa[td][r] * l_i[r];
    }
}

extern "C" void kernel_launch(void* const* d_in, const int* in_sizes, int n_in,
                              void* d_out, int out_size, void* d_ws, size_t ws_size,
                              hipStream_t stream) {
    const float* q    = (const float*)d_in[0];
    const float* k    = (const float*)d_in[1];
    const float* v    = (const float*)d_in[2];
    const float* bias = (const float*)d_in[3];
    const int*   mask = (const int*)d_in[4];
    float* out = (float*)d_out;

    dim3 grid(Sn / QT, Hn, Bn);   // (32, 16, 2)
    core_attn_kernel<<<grid, 256, 0, stream>>>(q, k, v, bias, mask, out);
}